// Round 6
// baseline (221.893 us; speedup 1.0000x reference)
//
#include <hip/hip_runtime.h>

typedef short bf16x8 __attribute__((ext_vector_type(8)));
typedef float f32x4  __attribute__((ext_vector_type(4)));
typedef unsigned int u32x2 __attribute__((ext_vector_type(2)));

#define B_SZ   2
#define T_SZ   2048
#define N_SZ   2048
#define HID_SZ 1024
#define NHEADS 16

// scale/sqrt(half) * log2(e), folded into Q at projection epilogue
#define SLOG2E 0.25500297f

static __device__ __forceinline__ float fexp2(float x) {
#if __has_builtin(__builtin_amdgcn_exp2f)
    return __builtin_amdgcn_exp2f(x);       // raw v_exp_f32
#else
    float r; __asm__("v_exp_f32 %0, %1" : "=v"(r) : "v"(x)); return r;
#endif
}

static __device__ __forceinline__ short f2bf(float f) {
    unsigned u = __float_as_uint(f);
    u = (u + 0x7fffu + ((u >> 16) & 1u)) >> 16;   // RNE
    return (short)u;
}

// pack two floats -> two bf16 (round-half-up) via v_perm_b32
static __device__ __forceinline__ unsigned pk2(float a, float b) {
#if __has_builtin(__builtin_amdgcn_perm)
    return __builtin_amdgcn_perm(__float_as_uint(b) + 0x8000u,
                                 __float_as_uint(a) + 0x8000u, 0x07060302u);
#else
    unsigned ua = (__float_as_uint(a) + 0x8000u) >> 16;
    unsigned ub = (__float_as_uint(b) + 0x8000u) & 0xffff0000u;
    return ua | ub;
#endif
}

// async global->LDS, 16B per lane; LDS dest = wave-uniform base + lane*16
static __device__ __forceinline__ void gload16(const void* g, void* l) {
    __builtin_amdgcn_global_load_lds(
        (const __attribute__((address_space(1))) unsigned int*)g,
        (__attribute__((address_space(3))) unsigned int*)l, 16, 0, 0);
}

#define MFMA16(a, b, c) __builtin_amdgcn_mfma_f32_16x16x32_bf16((a), (b), (c), 0, 0, 0)

// ---------------------------------------------------------------------------
// fp32 -> bf16 pre-convert (RNE), 8 elem/thread, all five tensors (46 MB).
// Restored (round-0 verified): proj is operand-TRAFFIC-bound; bf16 A-panels
// halve its dominant read traffic and delete the pk2/ds_write staging VALU.
// ---------------------------------------------------------------------------
__global__ __launch_bounds__(256) void cvt_kernel(
    const float* __restrict__ dec, const float* __restrict__ enc,
    const float* __restrict__ Wq, const float* __restrict__ Wk,
    const float* __restrict__ Wv,
    short* __restrict__ decb, short* __restrict__ encb,
    short* __restrict__ wqb, short* __restrict__ wkb, short* __restrict__ wvb)
{
    const float* src; short* dst; int n;
    switch (blockIdx.y) {
      case 0: src = dec; dst = decb; n = B_SZ * T_SZ * HID_SZ; break;
      case 1: src = enc; dst = encb; n = B_SZ * N_SZ * HID_SZ; break;
      case 2: src = Wq;  dst = wqb;  n = HID_SZ * HID_SZ;      break;
      case 3: src = Wk;  dst = wkb;  n = HID_SZ * HID_SZ;      break;
      default:src = Wv;  dst = wvb;  n = HID_SZ * HID_SZ;      break;
    }
    const int idx = (blockIdx.x * 256 + threadIdx.x) * 8;
    if (idx >= n) return;
    float4 a = *(const float4*)&src[idx];
    float4 b = *(const float4*)&src[idx + 4];
    bf16x8 r;
    r[0]=f2bf(a.x); r[1]=f2bf(a.y); r[2]=f2bf(a.z); r[3]=f2bf(a.w);
    r[4]=f2bf(b.x); r[5]=f2bf(b.y); r[6]=f2bf(b.z); r[7]=f2bf(b.w);
    *(bf16x8*)&dst[idx] = r;
}

// ---------------------------------------------------------------------------
// Projection GEMM, 256x256 tile for operand-traffic reduction:
// vs 128x128, A re-reads drop 8->4x and B 32->16x (traffic ~576 -> ~200 MB
// chip-wide; proj is BW-bound, so this is the lever). BK=64, 512 thr =
// 8 waves (2M x 4N), 128x64 output/wave, acc[8][4]. Both operands bf16 via
// cvt, staged with pure global_load_lds (pre-swizzled global source, linear
// LDS dest), double-buffered (128 KB LDS -> 1 block/CU), prefetch issued
// BEFORE compute, ONE barrier per K-iter (round-5 verified loop shape).
// Grid 192 (= 3 proj x 16 m-tiles x 4 c-tiles), XCD-swizzled so consecutive
// works share a B-panel (512 KB, L2-resident).
// Outputs:
//  proj 0: qbuf [4096,1024] row-major bf16, pre-scaled by SLOG2E
//  proj 1: kblk [(b*16+h)*32+nc][64 n][8 kg][8] — kg stored at (kg ^ (n&7))
//  proj 2: vblk [(b*16+h)*32+nc][64 vd][8 ng][8] — n' = (n&15)*4+((n>>4)&3),
//          ng stored at (ng ^ (vd&7))
// ---------------------------------------------------------------------------
__global__ __launch_bounds__(512, 2) void proj_kernel(
    const short* __restrict__ decb, const short* __restrict__ encb,
    const short* __restrict__ wqb, const short* __restrict__ wkb,
    const short* __restrict__ wvb,
    short* __restrict__ qbuf, short* __restrict__ kblk, short* __restrict__ vblk)
{
    const int i    = blockIdx.x;
    const int work = (i & 7) * 24 + (i >> 3);     // XCD-contiguous, 192 blocks
    const int proj = work >> 6;
    const int rem  = work & 63;
    const int c0   = (rem >> 4) * 256;
    const int m0   = (rem & 15) * 256;

    const short* __restrict__ X = (proj == 0) ? decb : encb;
    const short* __restrict__ W = (proj == 0) ? wqb : ((proj == 1) ? wkb : wvb);

    __shared__ short As[2][256 * 64];   // 64 KB double-buffered A
    __shared__ short Bs[2][256 * 64];   // 64 KB double-buffered B

    const int tid  = threadIdx.x;
    const int lane = tid & 63;
    const int w    = tid >> 6;          // 0..7
    const int wm   = (w >> 2) * 128;    // 2 wave-rows
    const int wn   = (w & 3) * 64;      // 4 wave-cols
    const int q4   = lane >> 4;
    const int r16  = lane & 15;

    const int srow = w * 32;                       // wave stages 32 rows each
    const int lrow = lane >> 3;                    // 0..7 within 8-row group
    const int chnk = lane & 7;                     // k-chunk owned by lane
    const int swz8 = ((chnk ^ lrow) * 8);          // pre-swizzled k-offset

    f32x4 acc[8][4] = {};

    // stage one 256x64 A-tile + B-tile into buffer `bufi` (4+4 gload16/thread)
#define PSTAGE(bufi, kbase) do {                                              \
    _Pragma("unroll")                                                         \
    for (int j = 0; j < 4; ++j) {                                             \
        const int row = srow + j * 8 + lrow;                                  \
        gload16(&X[(size_t)(m0 + row) * HID_SZ + (kbase) + swz8],             \
                &As[bufi][(srow + j * 8) * 64]);                              \
        gload16(&W[(size_t)(c0 + row) * HID_SZ + (kbase) + swz8],             \
                &Bs[bufi][(srow + j * 8) * 64]);                              \
    } } while (0)

    PSTAGE(0, 0);
    __syncthreads();   // drain: first tile ready

    for (int it = 0; it < 16; ++it) {
        const int cur = it & 1;

        // prefetch next K-tile into the other buffer; drained by the
        // end-of-iter barrier, so it flies under this iter's 128 MFMA.
        if (it < 15) PSTAGE(cur ^ 1, (it + 1) * 64);

#pragma unroll
        for (int kk = 0; kk < 2; ++kk) {
            bf16x8 af[8], bfr[4];
#pragma unroll
            for (int mi = 0; mi < 8; ++mi)
                af[mi] = *(const bf16x8*)&As[cur][(wm + mi * 16 + r16) * 64
                                                  + (((kk * 4 + q4) ^ (r16 & 7)) * 8)];
#pragma unroll
            for (int ni = 0; ni < 4; ++ni)
                bfr[ni] = *(const bf16x8*)&Bs[cur][(wn + ni * 16 + r16) * 64
                                                   + (((kk * 4 + q4) ^ (r16 & 7)) * 8)];
#pragma unroll
            for (int mi = 0; mi < 8; ++mi)
#pragma unroll
                for (int ni = 0; ni < 4; ++ni)
                    acc[mi][ni] = MFMA16(af[mi], bfr[ni], acc[mi][ni]);
        }

        __syncthreads();   // readers done + prefetch drained (vmcnt 0)
    }
#undef PSTAGE

#pragma unroll
    for (int mi = 0; mi < 8; ++mi)
#pragma unroll
    for (int ni = 0; ni < 4; ++ni)
#pragma unroll
    for (int r = 0; r < 4; ++r) {
        const int m = m0 + wm + mi * 16 + q4 * 4 + r;
        const int c = c0 + wn + ni * 16 + r16;
        const float v = acc[mi][ni][r];
        if (proj == 0) {
            qbuf[(size_t)m * HID_SZ + c] = f2bf(v * SLOG2E);
        } else {
            const int bb = m >> 11, n = m & (N_SZ - 1);
            const int hh = c >> 6;
            const int nc = n >> 6;
            const size_t base = ((size_t)((bb * NHEADS + hh) * 32 + nc)) * 4096;
            if (proj == 1) {
                const int row = n & 63, kd = c & 63;
                const int g = kd >> 3, e = kd & 7;
                kblk[base + row * 64 + (((g ^ (row & 7)) << 3) | e)] = f2bf(v);
            } else {
                const int vd = c & 63, nl = n & 63;
                const int np = ((nl & 15) << 2) | ((nl >> 4) & 3);
                const int g = np >> 3, e = np & 7;
                vblk[base + vd * 64 + (((g ^ (vd & 7)) << 3) | e)] = f2bf(v);
            }
        }
    }
}

// ---------------------------------------------------------------------------
// One 16-row t-slice of the differential attention chunk compute:
// QK^T -> exp2/pack -> wave-private P in LDS -> PV + l. Identical math/layout
// to the verified round-1 kernel body.
// ---------------------------------------------------------------------------
static __device__ __forceinline__ void attn_half(
    const short* __restrict__ Ks, const short* __restrict__ Vs,
    short* __restrict__ P,
    bf16x8 aq1, bf16x8 aq2, bf16x8 ones,
    f32x4 (&o0)[4], f32x4 (&o1)[4], f32x4& l0a, f32x4& l1a,
    int q4, int r16, int swz, int wg_half, int wlo)
{
    // QK from LDS
    const f32x4 zz = {0.f, 0.f, 0.f, 0.f};
    f32x4 s0[4], s1[4];
#pragma unroll
    for (int s = 0; s < 4; ++s) {
        const int row = s * 16 + r16;
        bf16x8 bk1 = *(const bf16x8*)&Ks[row * 64 + ((q4 ^ swz) << 3)];
        bf16x8 bk2 = *(const bf16x8*)&Ks[row * 64 + (((4 + q4) ^ swz) << 3)];
        s0[s] = MFMA16(aq1, bk1, zz);
        s1[s] = MFMA16(aq2, bk2, zz);
    }

    // exp2 + pack + wave-private LDS stage
#pragma unroll
    for (int r = 0; r < 4; ++r) {
        const int row = q4 * 4 + r;
        const int wo  = row * 64 + ((wg_half ^ (row & 7)) << 3) + wlo;
        u32x2 pw;
        pw[0] = pk2(fexp2(s0[0][r]), fexp2(s0[1][r]));
        pw[1] = pk2(fexp2(s0[2][r]), fexp2(s0[3][r]));
        *(u32x2*)&P[wo] = pw;
        pw[0] = pk2(fexp2(s1[0][r]), fexp2(s1[1][r]));
        pw[1] = pk2(fexp2(s1[2][r]), fexp2(s1[3][r]));
        *(u32x2*)&P[1024 + wo] = pw;
    }

    // PV + l from LDS (same-wave ds ordering makes P write->read safe)
#pragma unroll
    for (int kk = 0; kk < 2; ++kk) {
        const int ro = r16 * 64 + (((kk * 4 + q4) ^ swz) << 3);
        bf16x8 ap0 = *(const bf16x8*)&P[ro];
        bf16x8 ap1 = *(const bf16x8*)&P[1024 + ro];
        l0a = MFMA16(ap0, ones, l0a);
        l1a = MFMA16(ap1, ones, l1a);
#pragma unroll
        for (int d = 0; d < 4; ++d) {
            const int vd = d * 16 + r16;
            bf16x8 bv = *(const bf16x8*)&Vs[vd * 64 + (((kk * 4 + q4) ^ swz) << 3)];
            o0[d] = MFMA16(ap0, bv, o0[d]);
            o1[d] = MFMA16(ap1, bv, o1[d]);
        }
    }
}

// ---------------------------------------------------------------------------
// Differential flash attention, 8-wave blocks (round-5 verified, unchanged):
// 512 threads = 8 waves, each wave owns ONE 16-row t-slice. 4 waves/SIMD
// from 2 decorrelated blocks hides the MFMA->exp2->pack->ds chain.
// K/V double-buffered (32 KB) + 8x4KB P = 64 KB -> 2 blocks/CU, grid 512.
// One barrier per chunk; prefetch issued before compute. Softmax: raw
// v_exp_f32, no max (Q pre-scaled to log2 domain), l via MFMA-ones.
// ---------------------------------------------------------------------------
__global__ __launch_bounds__(512, 4) void attn_kernel(
    const short* __restrict__ qbuf, const short* __restrict__ kblk,
    const short* __restrict__ vblk,
    const float* __restrict__ lq1, const float* __restrict__ lq2,
    const float* __restrict__ lk1, const float* __restrict__ lk2,
    float* __restrict__ out)
{
    const int bi   = blockIdx.x;
    const int work = (bi & 7) * 64 + (bi >> 3);   // XCD-contiguous, 512 blocks
    const int t0   = (work & 15) * 128;
    const int hb   = work >> 4;
    const int h    = hb & 15;
    const int b    = hb >> 4;

    const int tid  = threadIdx.x;
    const int w    = tid >> 6;          // 0..7
    const int lane = tid & 63;
    const int q4   = lane >> 4;
    const int r16  = lane & 15;

    float d1 = 0.f, d2 = 0.f;
#pragma unroll
    for (int i = 0; i < 32; ++i) { d1 += lq1[i] * lk1[i]; d2 += lq2[i] * lk2[i]; }
    const float lam = __expf(d1) - __expf(d2) + 0.8f;

    __shared__ short Ks[2][4096];     // 16 KB double-buffered K
    __shared__ short Vs[2][4096];     // 16 KB double-buffered V
    __shared__ short Pl[8][2048];     // 32 KB per-wave P (2 comps x 16 x 64)
    short* __restrict__ P = &Pl[w][0];

    const int trow = t0 + w * 16 + r16;
    const short* qrow = qbuf + ((size_t)(b * T_SZ + trow)) * HID_SZ + h * 64;
    const bf16x8 aq1 = *(const bf16x8*)(qrow + q4 * 8);
    const bf16x8 aq2 = *(const bf16x8*)(qrow + 32 + q4 * 8);

    const short* kbh = kblk + ((size_t)(b * NHEADS + h)) * 32 * 4096;
    const short* vbh = vblk + ((size_t)(b * NHEADS + h)) * 32 * 4096;

    bf16x8 ones;
#pragma unroll
    for (int i = 0; i < 8; ++i) ones[i] = (short)0x3F80;   // bf16 1.0

    f32x4 o0[4] = {}, o1[4] = {};
    f32x4 l0a = {0.f,0.f,0.f,0.f}, l1a = {0.f,0.f,0.f,0.f};

    const int wg_half = (r16 >> 1);
    const int wlo     = (r16 & 1) * 4;
    const int swz     = r16 & 7;      // fragment-read unswizzle

    // prologue: stage chunk 0 into buffer 0 (8 waves x 1KB each for K and V)
    gload16(&kbh[w * 512 + lane * 8], &Ks[0][w * 512]);
    gload16(&vbh[w * 512 + lane * 8], &Vs[0][w * 512]);
    __syncthreads();   // drain: chunk 0 ready

    for (int nc = 0; nc < 32; ++nc) {
        const int cur = nc & 1;

        // prefetch chunk nc+1 into the other buffer; drained by the
        // end-of-chunk barrier, so it flies under this chunk's compute.
        if (nc + 1 < 32) {
            const short* Kg = kbh + (nc + 1) * 4096;
            const short* Vg = vbh + (nc + 1) * 4096;
            gload16(&Kg[w * 512 + lane * 8], &Ks[cur ^ 1][w * 512]);
            gload16(&Vg[w * 512 + lane * 8], &Vs[cur ^ 1][w * 512]);
        }

        attn_half(Ks[cur], Vs[cur], P, aq1, aq2, ones, o0, o1, l0a, l1a,
                  q4, r16, swz, wg_half, wlo);

        __syncthreads();   // drain prefetch + all waves done with cur
    }

    float rl0[4], rl1[4];
#pragma unroll
    for (int r = 0; r < 4; ++r) { rl0[r] = 1.f / l0a[r]; rl1[r] = lam / l1a[r]; }

#pragma unroll
    for (int d = 0; d < 4; ++d)
#pragma unroll
        for (int r = 0; r < 4; ++r) {
            const int t  = t0 + w * 16 + q4 * 4 + r;
            const int vd = d * 16 + r16;
            out[((size_t)(b * T_SZ + t)) * HID_SZ + h * 64 + vd] =
                o0[d][r] * rl0[r] - o1[d][r] * rl1[r];
        }
}

extern "C" void kernel_launch(void* const* d_in, const int* in_sizes, int n_in,
                              void* d_out, int out_size, void* d_ws, size_t ws_size,
                              hipStream_t stream)
{
    (void)in_sizes; (void)n_in; (void)out_size; (void)ws_size;

    const float* enc = (const float*)d_in[0];
    const float* dec = (const float*)d_in[1];
    const float* Wq  = (const float*)d_in[2];
    const float* Wk  = (const float*)d_in[3];
    const float* Wv  = (const float*)d_in[4];
    const float* lq1 = (const float*)d_in[5];
    const float* lq2 = (const float*)d_in[6];
    const float* lk1 = (const float*)d_in[7];
    const float* lk2 = (const float*)d_in[8];
    float* out = (float*)d_out;

    short* qbuf = (short*)d_ws;                          // [4096,1024]
    short* kblk = qbuf + (size_t)4096 * 1024;            // [32 bh][32 nc][4096]
    short* vblk = kblk + (size_t)4096 * 1024;            // [32 bh][32 nc][4096]
    short* decb = vblk + (size_t)4096 * 1024;            // [2,2048,1024]
    short* encb = decb + (size_t)2 * 2048 * 1024;        // [2,2048,1024]
    short* wqb  = encb + (size_t)2 * 2048 * 1024;        // [1024,1024]
    short* wkb  = wqb  + (size_t)1024 * 1024;
    short* wvb  = wkb  + (size_t)1024 * 1024;

    cvt_kernel<<<dim3(2048, 5), 256, 0, stream>>>(
        dec, enc, Wq, Wk, Wv, decb, encb, wqb, wkb, wvb);

    proj_kernel<<<192, 512, 0, stream>>>(
        decb, encb, wqb, wkb, wvb, qbuf, kblk, vblk);

    attn_kernel<<<512, 512, 0, stream>>>(
        qbuf, kblk, vblk, lq1, lq2, lk1, lk2, out);
}

// Round 7
// 192.694 us; speedup vs baseline: 1.1515x; 1.1515x over previous
//
#include <hip/hip_runtime.h>

typedef short bf16x8 __attribute__((ext_vector_type(8)));
typedef float f32x4  __attribute__((ext_vector_type(4)));
typedef unsigned int u32x2 __attribute__((ext_vector_type(2)));

#define B_SZ   2
#define T_SZ   2048
#define N_SZ   2048
#define HID_SZ 1024
#define NHEADS 16

// scale/sqrt(half) * log2(e), folded into Q at projection epilogue
#define SLOG2E 0.25500297f

static __device__ __forceinline__ float fexp2(float x) {
#if __has_builtin(__builtin_amdgcn_exp2f)
    return __builtin_amdgcn_exp2f(x);       // raw v_exp_f32
#else
    float r; __asm__("v_exp_f32 %0, %1" : "=v"(r) : "v"(x)); return r;
#endif
}

static __device__ __forceinline__ short f2bf(float f) {
    unsigned u = __float_as_uint(f);
    u = (u + 0x7fffu + ((u >> 16) & 1u)) >> 16;   // RNE
    return (short)u;
}

// pack two floats -> two bf16 (round-half-up) via v_perm_b32
static __device__ __forceinline__ unsigned pk2(float a, float b) {
#if __has_builtin(__builtin_amdgcn_perm)
    return __builtin_amdgcn_perm(__float_as_uint(b) + 0x8000u,
                                 __float_as_uint(a) + 0x8000u, 0x07060302u);
#else
    unsigned ua = (__float_as_uint(a) + 0x8000u) >> 16;
    unsigned ub = (__float_as_uint(b) + 0x8000u) & 0xffff0000u;
    return ua | ub;
#endif
}

// async global->LDS, 16B per lane; LDS dest = wave-uniform base + lane*16
static __device__ __forceinline__ void gload16(const void* g, void* l) {
    __builtin_amdgcn_global_load_lds(
        (const __attribute__((address_space(1))) unsigned int*)g,
        (__attribute__((address_space(3))) unsigned int*)l, 16, 0, 0);
}

#define MFMA16(a, b, c) __builtin_amdgcn_mfma_f32_16x16x32_bf16((a), (b), (c), 0, 0, 0)

// ---------------------------------------------------------------------------
// fp32 -> bf16 pre-convert (RNE), 8 elem/thread, all five tensors (46 MB).
// ---------------------------------------------------------------------------
__global__ __launch_bounds__(256) void cvt_kernel(
    const float* __restrict__ dec, const float* __restrict__ enc,
    const float* __restrict__ Wq, const float* __restrict__ Wk,
    const float* __restrict__ Wv,
    short* __restrict__ decb, short* __restrict__ encb,
    short* __restrict__ wqb, short* __restrict__ wkb, short* __restrict__ wvb)
{
    const float* src; short* dst; int n;
    switch (blockIdx.y) {
      case 0: src = dec; dst = decb; n = B_SZ * T_SZ * HID_SZ; break;
      case 1: src = enc; dst = encb; n = B_SZ * N_SZ * HID_SZ; break;
      case 2: src = Wq;  dst = wqb;  n = HID_SZ * HID_SZ;      break;
      case 3: src = Wk;  dst = wkb;  n = HID_SZ * HID_SZ;      break;
      default:src = Wv;  dst = wvb;  n = HID_SZ * HID_SZ;      break;
    }
    const int idx = (blockIdx.x * 256 + threadIdx.x) * 8;
    if (idx >= n) return;
    float4 a = *(const float4*)&src[idx];
    float4 b = *(const float4*)&src[idx + 4];
    bf16x8 r;
    r[0]=f2bf(a.x); r[1]=f2bf(a.y); r[2]=f2bf(a.z); r[3]=f2bf(a.w);
    r[4]=f2bf(b.x); r[5]=f2bf(b.y); r[6]=f2bf(b.z); r[7]=f2bf(b.w);
    *(bf16x8*)&dst[idx] = r;
}

// ---------------------------------------------------------------------------
// Projection GEMM, round-0 verified staging (128x128 tile, BK=64, 4 waves,
// single-buffered gload_lds both operands, 2 barriers/iter, 768 blocks =
// 3/CU) + NEW full-cacheline epilogue:
//   phase 1: scatter acc (scalar ds_write) into a 33KB LDS image laid out in
//            the FINAL global layout (swizzles baked in),
//   phase 2: lane-contiguous 16B/lane copies LDS->global covering complete
//            128B lines — eliminates the partial-line read-for-write (17 MB
//            excess FETCH) and dirty-line write amplification (10 MB excess
//            WRITE) that capped proj at 830 GB/s x 73 MB = 89 us.
// Outputs (unchanged layouts):
//  proj 0: qbuf [4096,1024] row-major bf16, pre-scaled by SLOG2E
//  proj 1: kblk [(b*16+h)*32+nc][64 n][8 kg][8] — kg stored at (kg ^ (n&7))
//  proj 2: vblk [(b*16+h)*32+nc][64 vd][8 ng][8] — n' = (n&15)*4+((n>>4)&3),
//          ng stored at (ng ^ (vd&7))
// ---------------------------------------------------------------------------
__global__ __launch_bounds__(256, 3) void proj_kernel(
    const short* __restrict__ decb, const short* __restrict__ encb,
    const short* __restrict__ wqb, const short* __restrict__ wkb,
    const short* __restrict__ wvb,
    short* __restrict__ qbuf, short* __restrict__ kblk, short* __restrict__ vblk)
{
    const int i    = blockIdx.x;
    const int work = (i & 7) * 96 + (i >> 3);     // XCD-contiguous work id
    const int proj = work >> 8;
    const int rem  = work & 255;
    const int c0   = (rem >> 5) * 128;
    const int m0   = (rem & 31) * 128;

    const short* __restrict__ X = (proj == 0) ? decb : encb;
    const short* __restrict__ W = (proj == 0) ? wqb : ((proj == 1) ? wkb : wvb);

    // pool: As(8192) + Bs(8192) shorts during K-loop; C-image (<=16896) after
    __shared__ short pool[16896];                 // 33792 B -> 3-4 blocks/CU
    short* As = pool;
    short* Bs = pool + 8192;

    const int tid  = threadIdx.x;
    const int lane = tid & 63;
    const int w    = tid >> 6;
    const int wm   = (w >> 1) * 64;
    const int wn   = (w & 1) * 64;
    const int q4   = lane >> 4;
    const int r16  = lane & 15;

    const int srow = w * 32;                       // wave stages 32 rows
    const int lrow = lane >> 3;                    // 0..7 within 8-row group
    const int lxor = (((lane & 7) ^ lrow) * 8);    // permuted k-offset (shorts)

    f32x4 acc[4][4] = {};

    for (int k0 = 0; k0 < HID_SZ; k0 += 64) {
        __syncthreads();   // prev iter's ds_reads done before overwrite
#pragma unroll
        for (int j = 0; j < 4; ++j) {
            const int row = srow + j * 8 + lrow;
            gload16(&X[(size_t)(m0 + row) * HID_SZ + k0 + lxor],
                    &As[(srow + j * 8) * 64]);
            gload16(&W[(size_t)(c0 + row) * HID_SZ + k0 + lxor],
                    &Bs[(srow + j * 8) * 64]);
        }
        __syncthreads();   // staging drained

#pragma unroll
        for (int kk = 0; kk < 2; ++kk) {
            bf16x8 af[4], bfr[4];
#pragma unroll
            for (int mi = 0; mi < 4; ++mi)
                af[mi] = *(const bf16x8*)&As[(wm + mi * 16 + r16) * 64
                                             + (((kk * 4 + q4) ^ (r16 & 7)) * 8)];
#pragma unroll
            for (int ni = 0; ni < 4; ++ni)
                bfr[ni] = *(const bf16x8*)&Bs[(wn + ni * 16 + r16) * 64
                                              + (((kk * 4 + q4) ^ (r16 & 7)) * 8)];
#pragma unroll
            for (int mi = 0; mi < 4; ++mi)
#pragma unroll
                for (int ni = 0; ni < 4; ++ni)
                    acc[mi][ni] = MFMA16(af[mi], bfr[ni], acc[mi][ni]);
        }
    }

    __syncthreads();   // all MFMA LDS reads done before pool reuse as C-image

    // ---- phase 1: scatter acc into LDS image at FINAL layout positions ----
    if (proj == 0) {
        // image: [row 0..127][col 0..127], row stride 132 (bank stagger)
#pragma unroll
        for (int mi = 0; mi < 4; ++mi)
#pragma unroll
        for (int ni = 0; ni < 4; ++ni)
#pragma unroll
        for (int r = 0; r < 4; ++r) {
            const int tr = wm + mi * 16 + q4 * 4 + r;
            const int cc = wn + ni * 16 + r16;
            pool[tr * 132 + cc] = f2bf(acc[mi][ni][r] * SLOG2E);
        }
    } else if (proj == 1) {
        // 4 blobs of 4096 shorts; each wave fills exactly one blob
        const int bl = ((wn >> 6) << 1) | (wm >> 6);
#pragma unroll
        for (int mi = 0; mi < 4; ++mi)
#pragma unroll
        for (int ni = 0; ni < 4; ++ni)
#pragma unroll
        for (int r = 0; r < 4; ++r) {
            const int row64 = mi * 16 + q4 * 4 + r;     // n & 63
            const int kd    = ni * 16 + r16;            // c & 63
            const int j = ((((kd >> 3) ^ (row64 & 7)) << 3) | (kd & 7));
            pool[bl * 4096 + row64 * 64 + j] = f2bf(acc[mi][ni][r]);
        }
    } else {
        const int bl = ((wn >> 6) << 1) | (wm >> 6);
#pragma unroll
        for (int mi = 0; mi < 4; ++mi)
#pragma unroll
        for (int ni = 0; ni < 4; ++ni)
#pragma unroll
        for (int r = 0; r < 4; ++r) {
            const int nl = mi * 16 + q4 * 4 + r;        // n & 63
            const int vd = ni * 16 + r16;               // c & 63
            const int np = ((nl & 15) << 2) | ((nl >> 4) & 3);
            const int j = ((((np >> 3) ^ (vd & 7)) << 3) | (np & 7));
            pool[bl * 4096 + vd * 64 + j] = f2bf(acc[mi][ni][r]);
        }
    }

    __syncthreads();   // image complete

    // ---- phase 2: lane-contiguous full-line LDS -> global copy ----
    if (proj == 0) {
        const int c16 = tid & 15;                 // 16 lanes x 16B = 256B/row
#pragma unroll
        for (int rnd = 0; rnd < 8; ++rnd) {
            const int row = rnd * 16 + (tid >> 4);
            *(bf16x8*)&qbuf[(size_t)(m0 + row) * HID_SZ + c0 + c16 * 8] =
                *(const bf16x8*)&pool[row * 132 + c16 * 8];
        }
    } else {
        short* __restrict__ dst = (proj == 1) ? kblk : vblk;
        const int bb  = m0 >> 11;
        const int hh0 = c0 >> 6;
        const int nc0 = (m0 >> 6) & 31;
#pragma unroll
        for (int bl = 0; bl < 4; ++bl) {
            const size_t base =
                ((size_t)((bb * NHEADS + hh0 + (bl >> 1)) * 32
                          + nc0 + (bl & 1))) * 4096;
#pragma unroll
            for (int r2 = 0; r2 < 2; ++r2) {
                const int s = (r2 * 256 + tid) * 8;   // 256 thr x 16B = 4KB
                *(bf16x8*)&dst[base + s] = *(const bf16x8*)&pool[bl * 4096 + s];
            }
        }
    }
}

// ---------------------------------------------------------------------------
// One 16-row t-slice of the differential attention chunk compute:
// QK^T -> exp2/pack -> wave-private P in LDS -> PV + l. (round-1 verified)
// ---------------------------------------------------------------------------
static __device__ __forceinline__ void attn_half(
    const short* __restrict__ Ks, const short* __restrict__ Vs,
    short* __restrict__ P,
    bf16x8 aq1, bf16x8 aq2, bf16x8 ones,
    f32x4 (&o0)[4], f32x4 (&o1)[4], f32x4& l0a, f32x4& l1a,
    int q4, int r16, int swz, int wg_half, int wlo)
{
    // QK from LDS
    const f32x4 zz = {0.f, 0.f, 0.f, 0.f};
    f32x4 s0[4], s1[4];
#pragma unroll
    for (int s = 0; s < 4; ++s) {
        const int row = s * 16 + r16;
        bf16x8 bk1 = *(const bf16x8*)&Ks[row * 64 + ((q4 ^ swz) << 3)];
        bf16x8 bk2 = *(const bf16x8*)&Ks[row * 64 + (((4 + q4) ^ swz) << 3)];
        s0[s] = MFMA16(aq1, bk1, zz);
        s1[s] = MFMA16(aq2, bk2, zz);
    }

    // exp2 + pack + wave-private LDS stage
#pragma unroll
    for (int r = 0; r < 4; ++r) {
        const int row = q4 * 4 + r;
        const int wo  = row * 64 + ((wg_half ^ (row & 7)) << 3) + wlo;
        u32x2 pw;
        pw[0] = pk2(fexp2(s0[0][r]), fexp2(s0[1][r]));
        pw[1] = pk2(fexp2(s0[2][r]), fexp2(s0[3][r]));
        *(u32x2*)&P[wo] = pw;
        pw[0] = pk2(fexp2(s1[0][r]), fexp2(s1[1][r]));
        pw[1] = pk2(fexp2(s1[2][r]), fexp2(s1[3][r]));
        *(u32x2*)&P[1024 + wo] = pw;
    }

    // PV + l from LDS (same-wave ds ordering makes P write->read safe)
#pragma unroll
    for (int kk = 0; kk < 2; ++kk) {
        const int ro = r16 * 64 + (((kk * 4 + q4) ^ swz) << 3);
        bf16x8 ap0 = *(const bf16x8*)&P[ro];
        bf16x8 ap1 = *(const bf16x8*)&P[1024 + ro];
        l0a = MFMA16(ap0, ones, l0a);
        l1a = MFMA16(ap1, ones, l1a);
#pragma unroll
        for (int d = 0; d < 4; ++d) {
            const int vd = d * 16 + r16;
            bf16x8 bv = *(const bf16x8*)&Vs[vd * 64 + (((kk * 4 + q4) ^ swz) << 3)];
            o0[d] = MFMA16(ap0, bv, o0[d]);
            o1[d] = MFMA16(ap1, bv, o1[d]);
        }
    }
}

// ---------------------------------------------------------------------------
// Differential flash attention, 8-wave blocks (round-5 verified, unchanged).
// ---------------------------------------------------------------------------
__global__ __launch_bounds__(512, 4) void attn_kernel(
    const short* __restrict__ qbuf, const short* __restrict__ kblk,
    const short* __restrict__ vblk,
    const float* __restrict__ lq1, const float* __restrict__ lq2,
    const float* __restrict__ lk1, const float* __restrict__ lk2,
    float* __restrict__ out)
{
    const int bi   = blockIdx.x;
    const int work = (bi & 7) * 64 + (bi >> 3);   // XCD-contiguous, 512 blocks
    const int t0   = (work & 15) * 128;
    const int hb   = work >> 4;
    const int h    = hb & 15;
    const int b    = hb >> 4;

    const int tid  = threadIdx.x;
    const int w    = tid >> 6;          // 0..7
    const int lane = tid & 63;
    const int q4   = lane >> 4;
    const int r16  = lane & 15;

    float d1 = 0.f, d2 = 0.f;
#pragma unroll
    for (int i = 0; i < 32; ++i) { d1 += lq1[i] * lk1[i]; d2 += lq2[i] * lk2[i]; }
    const float lam = __expf(d1) - __expf(d2) + 0.8f;

    __shared__ short Ks[2][4096];     // 16 KB double-buffered K
    __shared__ short Vs[2][4096];     // 16 KB double-buffered V
    __shared__ short Pl[8][2048];     // 32 KB per-wave P (2 comps x 16 x 64)
    short* __restrict__ P = &Pl[w][0];

    const int trow = t0 + w * 16 + r16;
    const short* qrow = qbuf + ((size_t)(b * T_SZ + trow)) * HID_SZ + h * 64;
    const bf16x8 aq1 = *(const bf16x8*)(qrow + q4 * 8);
    const bf16x8 aq2 = *(const bf16x8*)(qrow + 32 + q4 * 8);

    const short* kbh = kblk + ((size_t)(b * NHEADS + h)) * 32 * 4096;
    const short* vbh = vblk + ((size_t)(b * NHEADS + h)) * 32 * 4096;

    bf16x8 ones;
#pragma unroll
    for (int i = 0; i < 8; ++i) ones[i] = (short)0x3F80;   // bf16 1.0

    f32x4 o0[4] = {}, o1[4] = {};
    f32x4 l0a = {0.f,0.f,0.f,0.f}, l1a = {0.f,0.f,0.f,0.f};

    const int wg_half = (r16 >> 1);
    const int wlo     = (r16 & 1) * 4;
    const int swz     = r16 & 7;      // fragment-read unswizzle

    // prologue: stage chunk 0 into buffer 0 (8 waves x 1KB each for K and V)
    gload16(&kbh[w * 512 + lane * 8], &Ks[0][w * 512]);
    gload16(&vbh[w * 512 + lane * 8], &Vs[0][w * 512]);
    __syncthreads();   // drain: chunk 0 ready

    for (int nc = 0; nc < 32; ++nc) {
        const int cur = nc & 1;

        // prefetch chunk nc+1 into the other buffer; drained by the
        // end-of-chunk barrier, so it flies under this chunk's compute.
        if (nc + 1 < 32) {
            const short* Kg = kbh + (nc + 1) * 4096;
            const short* Vg = vbh + (nc + 1) * 4096;
            gload16(&Kg[w * 512 + lane * 8], &Ks[cur ^ 1][w * 512]);
            gload16(&Vg[w * 512 + lane * 8], &Vs[cur ^ 1][w * 512]);
        }

        attn_half(Ks[cur], Vs[cur], P, aq1, aq2, ones, o0, o1, l0a, l1a,
                  q4, r16, swz, wg_half, wlo);

        __syncthreads();   // drain prefetch + all waves done with cur
    }

    float rl0[4], rl1[4];
#pragma unroll
    for (int r = 0; r < 4; ++r) { rl0[r] = 1.f / l0a[r]; rl1[r] = lam / l1a[r]; }

#pragma unroll
    for (int d = 0; d < 4; ++d)
#pragma unroll
        for (int r = 0; r < 4; ++r) {
            const int t  = t0 + w * 16 + q4 * 4 + r;
            const int vd = d * 16 + r16;
            out[((size_t)(b * T_SZ + t)) * HID_SZ + h * 64 + vd] =
                o0[d][r] * rl0[r] - o1[d][r] * rl1[r];
        }
}

extern "C" void kernel_launch(void* const* d_in, const int* in_sizes, int n_in,
                              void* d_out, int out_size, void* d_ws, size_t ws_size,
                              hipStream_t stream)
{
    (void)in_sizes; (void)n_in; (void)out_size; (void)ws_size;

    const float* enc = (const float*)d_in[0];
    const float* dec = (const float*)d_in[1];
    const float* Wq  = (const float*)d_in[2];
    const float* Wk  = (const float*)d_in[3];
    const float* Wv  = (const float*)d_in[4];
    const float* lq1 = (const float*)d_in[5];
    const float* lq2 = (const float*)d_in[6];
    const float* lk1 = (const float*)d_in[7];
    const float* lk2 = (const float*)d_in[8];
    float* out = (float*)d_out;

    short* qbuf = (short*)d_ws;                          // [4096,1024]
    short* kblk = qbuf + (size_t)4096 * 1024;            // [32 bh][32 nc][4096]
    short* vblk = kblk + (size_t)4096 * 1024;            // [32 bh][32 nc][4096]
    short* decb = vblk + (size_t)4096 * 1024;            // [2,2048,1024]
    short* encb = decb + (size_t)2 * 2048 * 1024;        // [2,2048,1024]
    short* wqb  = encb + (size_t)2 * 2048 * 1024;        // [1024,1024]
    short* wkb  = wqb  + (size_t)1024 * 1024;
    short* wvb  = wkb  + (size_t)1024 * 1024;

    cvt_kernel<<<dim3(2048, 5), 256, 0, stream>>>(
        dec, enc, Wq, Wk, Wv, decb, encb, wqb, wkb, wvb);

    proj_kernel<<<768, 256, 0, stream>>>(
        decb, encb, wqb, wkb, wvb, qbuf, kblk, vblk);

    attn_kernel<<<512, 512, 0, stream>>>(
        qbuf, kblk, vblk, lq1, lq2, lk1, lk2, out);
}